// Round 4
// baseline (964.084 us; speedup 1.0000x reference)
//
#include <hip/hip_runtime.h>
#include <hip/hip_cooperative_groups.h>
#include <stdint.h>

namespace cg = cooperative_groups;

#define N_NODES 50000
#define N_EDGES 800000
#define D 512
#define M_PAD 50048    // 391 * 128
#define SCAN_NB 196    // 196*256 = 50176 >= N_NODES
#define CSR_BLOCKS 1024

typedef __attribute__((ext_vector_type(8))) __bf16 bf16x8;
typedef __attribute__((ext_vector_type(4))) float f32x4;

static __device__ __forceinline__ unsigned short f2bf(float f) {
  unsigned u = __float_as_uint(f);
  u += 0x7fff + ((u >> 16) & 1);   // round-to-nearest-even
  return (unsigned short)(u >> 16);
}
static __device__ __forceinline__ float bf2f(unsigned short h) {
  return __uint_as_float(((unsigned)h) << 16);
}

// async global->LDS, 16B per lane; LDS base must be wave-uniform (lane-linear fill)
static __device__ __forceinline__ void gload_lds16(const void* g, void* l) {
  __builtin_amdgcn_global_load_lds((const __attribute__((address_space(1))) unsigned*)g,
                                   (__attribute__((address_space(3))) unsigned*)l, 16, 0, 0);
}

// =======================================================================
// Cooperative kernel: converts X->bf16 (padded), W->Wt bf16, and builds the
// dst-CSR (zero / hist / scan / fill) with grid.sync between phases.
// Replaces 7 separate launches.
// =======================================================================
__global__ __launch_bounds__(256) void k_csr(const float* __restrict__ x,
                                             const float* __restrict__ w,
                                             unsigned short* __restrict__ xb,
                                             unsigned short* __restrict__ wt,
                                             const int* __restrict__ esrc,
                                             const int* __restrict__ edst,
                                             const float* __restrict__ ew,
                                             int* __restrict__ deg,
                                             int* __restrict__ off,
                                             int* __restrict__ cur,
                                             int* __restrict__ csrc,
                                             float* __restrict__ cw,
                                             int* __restrict__ bsum) {
  cg::grid_group grid = cg::this_grid();
  __shared__ int red[256];
  const int gtid = blockIdx.x * 256 + threadIdx.x;
  const int gsz  = gridDim.x * 256;

  // ---- phase A: convert X (float4 chunks, zero-pad), convert W^T, zero deg ----
  const int nchunk = M_PAD * D / 4;
  for (int i = gtid; i < nchunk; i += gsz) {
    long long base = (long long)i * 4;
    int row = (int)(base >> 9);   // D = 512
    ushort4 o;
    if (row < N_NODES) {
      float4 v = *(const float4*)(x + base);
      o.x = f2bf(v.x); o.y = f2bf(v.y); o.z = f2bf(v.z); o.w = f2bf(v.w);
    } else {
      o.x = 0; o.y = 0; o.z = 0; o.w = 0;
    }
    *(ushort4*)(xb + base) = o;
  }
  for (int i = gtid; i < D * D; i += gsz) {
    int k = i >> 9, n = i & 511;
    wt[n * D + k] = f2bf(w[i]);   // coalesced read, scattered 2B write (0.5 MB)
  }
  for (int i = gtid; i < N_NODES; i += gsz) deg[i] = 0;
  grid.sync();

  // ---- phase B: histogram of destinations ----
  for (int e = gtid; e < N_EDGES; e += gsz) atomicAdd(&deg[edst[e]], 1);
  grid.sync();

  // ---- phase C1: per-256-chunk sums (blocks 0..SCAN_NB-1) ----
  if (blockIdx.x < SCAN_NB) {
    int i = blockIdx.x * 256 + threadIdx.x;
    red[threadIdx.x] = (i < N_NODES) ? deg[i] : 0;
    __syncthreads();
#pragma unroll
    for (int s = 128; s > 0; s >>= 1) {
      if ((int)threadIdx.x < s) red[threadIdx.x] += red[threadIdx.x + s];
      __syncthreads();
    }
    if (threadIdx.x == 0) bsum[blockIdx.x] = red[0];
  }
  grid.sync();

  // ---- phase C2: exclusive scan of chunk sums (block 0) ----
  if (blockIdx.x == 0) {
    int t = threadIdx.x;
    int v = (t < SCAN_NB) ? bsum[t] : 0;
    red[t] = v;
    __syncthreads();
#pragma unroll
    for (int s = 1; s < 256; s <<= 1) {
      int add = (t >= s) ? red[t - s] : 0;
      __syncthreads();
      red[t] += add;
      __syncthreads();
    }
    if (t < SCAN_NB) bsum[t] = red[t] - v;
  }
  grid.sync();

  // ---- phase C3: intra-chunk scan + write off/cur ----
  if (blockIdx.x < SCAN_NB) {
    int t = threadIdx.x, i = blockIdx.x * 256 + t;
    int v = (i < N_NODES) ? deg[i] : 0;
    red[t] = v;
    __syncthreads();
#pragma unroll
    for (int s = 1; s < 256; s <<= 1) {
      int add = (t >= s) ? red[t - s] : 0;
      __syncthreads();
      red[t] += add;
      __syncthreads();
    }
    int pre = red[t] - v + bsum[blockIdx.x];
    if (i < N_NODES) {
      off[i] = pre;
      cur[i] = pre;
      if (i == N_NODES - 1) off[N_NODES] = pre + v;
    }
  }
  grid.sync();

  // ---- phase D: bucket fill ----
  for (int e = gtid; e < N_EDGES; e += gsz) {
    int d = edst[e];
    int p = atomicAdd(&cur[d], 1);
    csrc[p] = esrc[e];
    cw[p]   = ew[e];
  }
}

// =======================================================================
// bf16 GEMM: C[M_PAD x D] = A * Bt^T, 128x128 tile, global_load_lds staging
// =======================================================================
__global__ __launch_bounds__(256) void k_gemm(const unsigned short* __restrict__ A,
                                              const unsigned short* __restrict__ Bt,
                                              unsigned short* __restrict__ C) {
  __shared__ unsigned short lds_a[128 * 32];
  __shared__ unsigned short lds_b[128 * 32];
  const int tid  = threadIdx.x;
  const int bm   = blockIdx.x >> 2;   // 391
  const int bn   = blockIdx.x & 3;    // 4
  const int m0   = bm * 128, n0 = bn * 128;
  const int wave = tid >> 6, lane = tid & 63;
  const int wm   = wave & 1, wn = wave >> 1;
  const int l15  = lane & 15, quad = lane >> 4;

  f32x4 acc[4][4];
#pragma unroll
  for (int i = 0; i < 4; i++)
#pragma unroll
    for (int j = 0; j < 4; j++) acc[i][j] = f32x4{0.f, 0.f, 0.f, 0.f};

  for (int kt = 0; kt < D / 32; ++kt) {
    const int k0 = kt * 32;
    __syncthreads();
#pragma unroll
    for (int c = 0; c < 2; c++) {
      int i = c * 256 + wave * 64 + lane;   // 16B chunk id, lane-linear per wave
      int r = i >> 2, kc = (i & 3) << 3;
      gload_lds16(&A[(long long)(m0 + r) * D + k0 + kc], &lds_a[(c * 256 + wave * 64) * 8]);
      gload_lds16(&Bt[(long long)(n0 + r) * D + k0 + kc], &lds_b[(c * 256 + wave * 64) * 8]);
    }
    __syncthreads();
    bf16x8 af[4], bfr[4];
#pragma unroll
    for (int t = 0; t < 4; t++) {
      af[t]  = *(const bf16x8*)&lds_a[(wm * 64 + t * 16 + l15) * 32 + quad * 8];
      bfr[t] = *(const bf16x8*)&lds_b[(wn * 64 + t * 16 + l15) * 32 + quad * 8];
    }
#pragma unroll
    for (int i = 0; i < 4; i++)
#pragma unroll
      for (int j = 0; j < 4; j++)
        acc[i][j] = __builtin_amdgcn_mfma_f32_16x16x32_bf16(af[i], bfr[j], acc[i][j], 0, 0, 0);
  }
#pragma unroll
  for (int i = 0; i < 4; i++)
#pragma unroll
    for (int j = 0; j < 4; j++)
#pragma unroll
      for (int r = 0; r < 4; r++) {
        int row = m0 + wm * 64 + i * 16 + quad * 4 + r;
        int col = n0 + wn * 64 + j * 16 + l15;
        C[(long long)row * D + col] = f2bf(acc[i][j][r]);
      }
}

// =======================================================================
// aggregate: ONE WAVE per dst node (4 nodes / 256-thread block).
// Edge meta loaded once coalesced, shfl-broadcast; 4-deep gather pipeline;
// no LDS, no syncthreads, no cross-wave combine.
// =======================================================================
static __device__ __forceinline__ void edge_fma(float (&a)[8], uint4 v, float w) {
  a[0] = fmaf(w, bf2f((unsigned short)(v.x & 0xffffu)), a[0]);
  a[1] = fmaf(w, bf2f((unsigned short)(v.x >> 16)),     a[1]);
  a[2] = fmaf(w, bf2f((unsigned short)(v.y & 0xffffu)), a[2]);
  a[3] = fmaf(w, bf2f((unsigned short)(v.y >> 16)),     a[3]);
  a[4] = fmaf(w, bf2f((unsigned short)(v.z & 0xffffu)), a[4]);
  a[5] = fmaf(w, bf2f((unsigned short)(v.z >> 16)),     a[5]);
  a[6] = fmaf(w, bf2f((unsigned short)(v.w & 0xffffu)), a[6]);
  a[7] = fmaf(w, bf2f((unsigned short)(v.w >> 16)),     a[7]);
}

__global__ __launch_bounds__(256) void k_agg(const int* __restrict__ off,
                                             const int* __restrict__ csrc,
                                             const float* __restrict__ cw,
                                             const unsigned short* __restrict__ S,
                                             float* __restrict__ out) {
  const int wave = threadIdx.x >> 6, lane = threadIdx.x & 63;
  const int node = blockIdx.x * 4 + wave;
  if (node >= N_NODES) return;
  const int start = off[node], end = off[node + 1];
  float a[8];
#pragma unroll
  for (int k = 0; k < 8; k++) a[k] = 0.f;

  for (int base = start; base < end; base += 64) {
    int m = end - base; if (m > 64) m = 64;
    int   c  = 0;
    float wv = 0.f;
    if (lane < m) { c = csrc[base + lane]; wv = cw[base + lane]; }  // coalesced, once per 64 edges
    int j = 0;
    for (; j + 4 <= m; j += 4) {
      int   s0 = __shfl(c, j),      s1 = __shfl(c, j + 1);
      int   s2 = __shfl(c, j + 2),  s3 = __shfl(c, j + 3);
      float w0 = __shfl(wv, j),     w1 = __shfl(wv, j + 1);
      float w2 = __shfl(wv, j + 2), w3 = __shfl(wv, j + 3);
      uint4 v0 = *(const uint4*)(S + (size_t)s0 * D + lane * 8);
      uint4 v1 = *(const uint4*)(S + (size_t)s1 * D + lane * 8);
      uint4 v2 = *(const uint4*)(S + (size_t)s2 * D + lane * 8);
      uint4 v3 = *(const uint4*)(S + (size_t)s3 * D + lane * 8);
      edge_fma(a, v0, w0);
      edge_fma(a, v1, w1);
      edge_fma(a, v2, w2);
      edge_fma(a, v3, w3);
    }
    for (; j < m; j++) {
      int   s0 = __shfl(c, j);
      float w0 = __shfl(wv, j);
      uint4 v0 = *(const uint4*)(S + (size_t)s0 * D + lane * 8);
      edge_fma(a, v0, w0);
    }
  }
  float4* o = (float4*)(out + (size_t)node * D + lane * 8);
  o[0] = make_float4(a[0], a[1], a[2], a[3]);
  o[1] = make_float4(a[4], a[5], a[6], a[7]);
}

extern "C" void kernel_launch(void* const* d_in, const int* in_sizes, int n_in,
                              void* d_out, int out_size, void* d_ws, size_t ws_size,
                              hipStream_t stream) {
  const float* x    = (const float*)d_in[0];
  const float* w    = (const float*)d_in[1];
  const float* ew   = (const float*)d_in[2];
  const int*   esrc = (const int*)d_in[3];
  const int*   edst = (const int*)d_in[4];
  float* out = (float*)d_out;

  char* p = (char*)d_ws;
  auto align256 = [](size_t v) { return (v + 255) & ~(size_t)255; };
  unsigned short* xb = (unsigned short*)p;  p += align256((size_t)M_PAD * D * 2);
  unsigned short* sb = (unsigned short*)p;  p += align256((size_t)M_PAD * D * 2);
  unsigned short* wt = (unsigned short*)p;  p += align256((size_t)D * D * 2);
  int*   deg  = (int*)p;   p += align256((size_t)N_NODES * 4);
  int*   off  = (int*)p;   p += align256((size_t)(N_NODES + 1) * 4);
  int*   cur  = (int*)p;   p += align256((size_t)N_NODES * 4);
  int*   csrc = (int*)p;   p += align256((size_t)N_EDGES * 4);
  float* cw   = (float*)p; p += align256((size_t)N_EDGES * 4);
  int*   bsum = (int*)p;   p += align256((size_t)256 * 4);

  // node 1: conversions + CSR build (cooperative, grid.sync between phases)
  void* args[] = { (void*)&x, (void*)&w, (void*)&xb, (void*)&wt,
                   (void*)&esrc, (void*)&edst, (void*)&ew,
                   (void*)&deg, (void*)&off, (void*)&cur,
                   (void*)&csrc, (void*)&cw, (void*)&bsum };
  hipLaunchCooperativeKernel((void*)k_csr, dim3(CSR_BLOCKS), dim3(256), args, 0, stream);
  // node 2: support = X @ W  (bf16 MFMA, output bf16)
  k_gemm<<<391 * 4, 256, 0, stream>>>(xb, wt, sb);
  // node 3: aggregate, one wave per node
  k_agg<<<N_NODES / 4, 256, 0, stream>>>(off, csrc, cw, sb, out);
}